// Round 14
// baseline (108.286 us; speedup 1.0000x reference)
//
#include <hip/hip_runtime.h>
#include <hip/hip_bf16.h>

// Problem constants
#define BATCH 2
#define GRP   2
#define NBG   4            // BATCH*GRP
#define CINCH 192          // input channels
#define OG    192          // output channels per group
#define HWDIM 48
#define LPIX  2304         // 48*48
#define KTAP  25           // 5x5
#define IDIM  4800         // CINCH*KTAP
#define NCHUNK 150         // IDIM/32
#define XPAD  24576        // padding each side of g_xt
#define LROW  400          // LDS bytes per staged B row (384 data + 16 pad)
#define ZOFF  (68 * LROW)  // zero region offset (27200); window = 68 rows
#define AOFF  (ZOFF + 1024) // A double-buffer offset; LDS total = AOFF + 16384

typedef __attribute__((ext_vector_type(4))) float  float4v;
typedef __attribute__((ext_vector_type(8))) short  short8;

// Static device scratch
// A, fragment-major: [bg][t][ot(3)][i(4)][m(16)][q(4)][e(8)] bf16
__device__ __align__(16) unsigned short g_wa[(size_t)NBG * NCHUNK * 6144];
__device__ __align__(16) unsigned short g_xt[XPAD + BATCH * LPIX * CINCH + XPAD]; // [b][l][c] bf16, padded
__device__ unsigned long long g_m64[NBG * LPIX];   // 50 mask bits per (bg,l)

__device__ __forceinline__ unsigned short f2bf(float f) {
  union { float f; unsigned int u; } un; un.f = f;
  unsigned int u = un.u;
  return (unsigned short)((u + 0x7fffu + ((u >> 16) & 1u)) >> 16);  // RNE
}

// ---------------------------------------------------------------------------
// ONE prep dispatch, block ranges:
//  [0,216)      transpose+cvt x -> g_xt
//  [216,984)    reorder dkw -> g_wa (fragment-major, coalesced 64B stores)
//  [984,1176)   mask bits -> g_m64
//  [1176,1200)  zero g_xt pads
__global__ __launch_bounds__(256) void prep(
    const float* __restrict__ x, const int* __restrict__ tg,
    const float* __restrict__ dkw) {
  __shared__ __align__(16) unsigned char smem[19200];
  const int bx = blockIdx.x, tid = threadIdx.x;

  if (bx < 216) {  // ---- transpose: 64c x 64l tiles via LDS (stride 68)
    unsigned short* tile = (unsigned short*)smem;
    const int c0 = (bx % 3) * 64;
    const int l0 = ((bx / 3) % 36) * 64;
    const int b  = bx / 108;
    #pragma unroll
    for (int it = 0; it < 4; ++it) {
      const int idx = it * 256 + tid;
      const int cl = idx >> 4, lq = idx & 15;
      const float4 v = reinterpret_cast<const float4*>(
          x + ((size_t)b * CINCH + c0 + cl) * LPIX + l0)[lq];
      unsigned short pk4[4] = {f2bf(v.x), f2bf(v.y), f2bf(v.z), f2bf(v.w)};
      *reinterpret_cast<uint2*>(&tile[cl * 68 + lq * 4]) =
          *reinterpret_cast<const uint2*>(pk4);
    }
    __syncthreads();
    unsigned short* dst = g_xt + XPAD + ((size_t)b * LPIX) * CINCH;
    #pragma unroll
    for (int it = 0; it < 2; ++it) {
      const int idx = it * 256 + tid;
      const int c8 = idx & 7, ll = idx >> 3;
      unsigned short pk[8];
      #pragma unroll
      for (int e = 0; e < 8; ++e) pk[e] = tile[(c8 * 8 + e) * 68 + ll];
      *reinterpret_cast<uint4*>(dst + (size_t)(l0 + ll) * CINCH + c0 + c8 * 8) =
          *reinterpret_cast<const uint4*>(pk);
    }
  } else if (bx < 984) {  // ---- weight reorder, fragment-major
    float* row = (float*)smem;                 // 4800 floats
    const int blk = bx - 216;                  // bg*192 + o
    const int bg = blk / OG, o = blk % OG;
    const float* src = dkw + (size_t)blk * IDIM;
    for (int i = tid; i < IDIM / 4; i += 256)
      reinterpret_cast<float4*>(row)[i] = reinterpret_cast<const float4*>(src)[i];
    __syncthreads();
    const int ot = o >> 6, fi = (o >> 4) & 3, m = o & 15;
    unsigned short* wbase =
        g_wa + (size_t)bg * NCHUNK * 6144 + ot * 2048 + fi * 512 + m * 32;
    for (int t = tid; t < NCHUNK; t += 256) {  // one 64B granule per t
      const int kk = t / 6, c0 = (t % 6) * 32;
      unsigned int pk[16];
      #pragma unroll
      for (int q = 0; q < 4; ++q)
        #pragma unroll
        for (int e = 0; e < 4; ++e) {
          const int c = c0 + q * 8 + e * 2;
          const unsigned lo = f2bf(row[c * KTAP + kk]);
          const unsigned hi = f2bf(row[(c + 1) * KTAP + kk]);
          pk[q * 4 + e] = lo | (hi << 16);
        }
      unsigned short* dst = wbase + (size_t)t * 6144;
      #pragma unroll
      for (int q = 0; q < 4; ++q)
        reinterpret_cast<uint4*>(dst)[q] = *reinterpret_cast<const uint4*>(pk + q * 4);
    }
  } else if (bx < 1176) {  // ---- mask bits
    const int blk = bx - 984;                  // bg*48 + h
    const int bg = blk / HWDIM, h = blk % HWDIM;
    const int b = bg >> 1, g = bg & 1;
    int* tgs = (int*)smem;                     // [2][5][48]
    for (int i = tid; i < 480; i += 256) {
      const int g2 = i / 240, r5 = (i / 48) % 5, w = i % 48;
      const int hh = h + r5 - 2;
      tgs[i] = (hh >= 0 && hh < HWDIM)
                   ? tg[((b * GRP + g2) * HWDIM + hh) * HWDIM + w]
                   : 0x7fffffff;
    }
    __syncthreads();
    if (tid < HWDIM) {
      const int w = tid;
      const int center = tgs[g * 240 + 96 + w];
      unsigned long long bits = 0ull;
      #pragma unroll
      for (int g2 = 0; g2 < GRP; ++g2)
        #pragma unroll
        for (int kk = 0; kk < KTAP; ++kk) {
          const int ww = w + kk % 5 - 2;
          if (ww >= 0 && ww < HWDIM && tgs[g2 * 240 + (kk / 5) * 48 + ww] < center)
            bits |= 1ull << (g2 * KTAP + kk);
        }
      g_m64[bg * LPIX + h * HWDIM + w] = bits;
    }
  } else {  // ---- zero g_xt pads (2 x 48 KiB)
    const int idx = (bx - 1176) * 256 + tid;   // 0..6143, 16B each
    uint4 z; z.x = z.y = z.z = z.w = 0u;
    if (idx < 3072)
      reinterpret_cast<uint4*>(g_xt)[idx] = z;
    else
      reinterpret_cast<uint4*>(g_xt + XPAD + (size_t)BATCH * LPIX * CINCH)[idx - 3072] = z;
  }
}

// ---------------------------------------------------------------------------
// GEMM (R25): FULL-K blocks -- no K-split, no partials, no reduce kernel.
// Each block owns an o64 x l64 output tile and loops over all 5 kernel
// rows: per ks it re-stages the 68-row B window (27.2 KB, between two
// barriers) and runs the R17-style 2-pair A double-buffer over that row's
// 30 chunks. Global pair index pp = ks*15+pt keeps buffer parity
// persistent so the A DMA prefetch crosses ks boundaries. All loop bounds
// are compile-time (R21 lesson) -> fully unrolled. Grid = 4bg x 3otile x
// 36ltile = 432 blocks, ALL co-resident (LDS 44.6 KB -> >=2 blocks/CU,
// 432 < 512 slots): zero dispatch-round quantization. f32 accumulate over
// full K, + bias, direct f32 out (better accuracy than bf16 partials).
// No atomics, no fences (R20/R23 lessons). Wave tile o64 x l16, acc[4].
__global__ __launch_bounds__(256, 2) void gemm_masked(
    const float* __restrict__ dkb, float* __restrict__ out) {
  __shared__ __align__(16) unsigned char sB[AOFF + 16384];

  const int n = blockIdx.x;                  // 0..431
  const int m = ((n & 7) * 54) + (n >> 3);   // XCD-contiguous work id (432=8*54)
  const int ltile = m % 36;                  // l-tile of 64
  const int s  = m / 36;                     // 0..11 = (otile, bg)
  const int otile = s % 3;
  const int bg = s / 3;
  const int b  = bg >> 1;
  const int lbase = ltile * 64, obase = otile * 64;
  const int tid = threadIdx.x, lane = tid & 63, wv = tid >> 6;
  const int q = lane >> 4, m16 = lane & 15;

  // per-thread A source: granule tid (16B) of chunk c's 4KB otile slab
  const unsigned short* abase =
      g_wa + (size_t)bg * NCHUNK * 6144 + otile * 2048 + tid * 8;

  // async 16B global->LDS; lds side = wave-uniform base + lane*16
#define GLL(gsrc, ldsoff)                                                     \
  __builtin_amdgcn_global_load_lds(                                           \
      (const __attribute__((address_space(1))) void*)(gsrc),                  \
      (__attribute__((address_space(3))) void*)(sB + (ldsoff)), 16, 0, 0);
  // stage window for kernel row ks: rows [wl0, wl0+67] contiguous in g_xt
#define STAGE_WIN(ks)                                                         \
  {                                                                           \
    const int wl0 = lbase + ((ks) - 2) * HWDIM - 2;                           \
    const unsigned short* xwin =                                              \
        g_xt + XPAD + (ptrdiff_t)(b * LPIX + wl0) * CINCH;                    \
    _Pragma("unroll")                                                         \
    for (int it = 0; it < 7; ++it) {       /* 68*24 = 1632 granules */        \
      const int i = it * 256 + tid;                                           \
      if (it < 6 || i < 1632) {                                               \
        const int r = i / 24, g = i % 24;                                     \
        *reinterpret_cast<uint4*>(sB + r * LROW + g * 16) =                   \
            *reinterpret_cast<const uint4*>(xwin + i * 8);                    \
      }                                                                       \
    }                                                                         \
  }

  // ---- per-lane mask bits (l16 fragment) and LDS base offset
  const int lj = wv * 16 + m16;
  const unsigned long long bits64 = g_m64[bg * LPIX + lbase + lj];
  const unsigned bl0 = (unsigned)(bits64 & 0x1ffffffull);
  const unsigned bh0 = (unsigned)((bits64 >> KTAP) & 0x1ffffffull);
  const unsigned bboff = lj * LROW + q * 16;
  const unsigned zoff = ZOFF + m16 * 64 + q * 16;   // lane-spread zero read

  float4v acc[4];
  #pragma unroll
  for (int i = 0; i < 4; ++i) acc[i] = (float4v)(0.0f);

  // ---- prologue: A pair 0 DMA, window(0), zero region
  GLL(abase,        AOFF + 0 * 8192 + wv * 1024)
  GLL(abase + 6144, AOFF + 0 * 8192 + wv * 1024 + 4096)
  STAGE_WIN(0)
  if (tid < 64) {  // zero region: 1 KB, tiles all 32 banks
    uint4 z; z.x = z.y = z.z = z.w = 0u;
    *reinterpret_cast<uint4*>(sB + ZOFF + tid * 16) = z;
  }
  __syncthreads();   // window(0) + A pair 0 visible

  #pragma unroll
  for (int ks = 0; ks < 5; ++ks) {
    const unsigned bls = bl0 >> (ks * 5);
    const unsigned bhs = bh0 >> (ks * 5);
    #pragma unroll
    for (int pt = 0; pt < 15; ++pt) {
      const int pp = ks * 15 + pt;           // global pair 0..74
      // issue A DMA for pair pp+1 into the other buffer (prefetch may
      // belong to the NEXT kernel row -- A is window-independent)
      if (pp < 74) {
        const unsigned short* src = abase + (size_t)(2 * pp + 2) * 6144;
        const int boff = AOFF + ((pp + 1) & 1) * 8192 + wv * 1024;
        GLL(src,        boff)
        GLL(src + 6144, boff + 4096)
      }
      // compute pair pp from A buffer (pp&1), window(ks)
      #pragma unroll
      for (int cc = 0; cc < 2; ++cc) {
        const int tl = 2 * pt + cc;          // chunk-in-row 0..29
        const int kt = tl / 6, ci = tl % 6;
        const unsigned char* ab = sB + AOFF + (pp & 1) * 8192 + cc * 4096;
        short8 Afr[4];
        #pragma unroll
        for (int i = 0; i < 4; ++i)
          Afr[i] = *reinterpret_cast<const short8*>(ab + i * 1024 + m16 * 64 + q * 16);
        const unsigned bit = (((ci >= 3) ? bhs : bls) >> kt) & 1u;
        const unsigned off = bit ? (bboff + kt * LROW + ci * 64) : zoff;
        const short8 Bfr = *reinterpret_cast<const short8*>(sB + off);
        #pragma unroll
        for (int i = 0; i < 4; ++i)
          acc[i] = __builtin_amdgcn_mfma_f32_16x16x32_bf16(Afr[i], Bfr,
                                                           acc[i], 0, 0, 0);
      }
      // barriers: normal pair -> one barrier; ks boundary -> drain reads,
      // restage window for ks+1, publish (two barriers)
      if (pt == 14) {
        if (ks < 4) {
          __syncthreads();                   // all reads of window(ks) done
          STAGE_WIN(ks + 1)
          __syncthreads();                   // window(ks+1) + pair pp+1 ready
        }
      } else {
        __syncthreads();                     // publishes pair pp+1
      }
    }
  }
#undef STAGE_WIN
#undef GLL

  // ---- epilogue: f32 out = acc + bias (direct, no partials).
  // C/D layout: col = lane&15 (l), row = q*4 + r (o).
  const int l = lbase + wv * 16 + m16;
  #pragma unroll
  for (int i = 0; i < 4; ++i) {
    const int og = obase + i * 16 + q * 4;
    #pragma unroll
    for (int r = 0; r < 4; ++r)
      out[((size_t)bg * OG + og + r) * LPIX + l] = acc[i][r] + dkb[bg * OG + og + r];
  }
}

// ---------------------------------------------------------------------------
extern "C" void kernel_launch(void* const* d_in, const int* in_sizes, int n_in,
                              void* d_out, int out_size, void* d_ws, size_t ws_size,
                              hipStream_t stream) {
  const float* x   = (const float*)d_in[0];
  const int*   tg  = (const int*)d_in[1];
  const float* dkw = (const float*)d_in[2];
  const float* dkb = (const float*)d_in[3];
  float* out = (float*)d_out;

  prep<<<dim3(1200), 256, 0, stream>>>(x, tg, dkw);
  gemm_masked<<<dim3(432), 256, 0, stream>>>(dkb, out);
}